// Round 2
// baseline (488.647 us; speedup 1.0000x reference)
//
#include <hip/hip_runtime.h>
#include <hip/hip_bf16.h>

// OutlookAttention: B=8,H=56,W=56,C=192,heads=6,K=3,pad=1 — fp32 in/out
constexpr int NH = 56;
constexpr int NW = 56;
constexpr int NC = 192;
constexpr int NKK = 9;          // K*K
constexpr int AJ = 486;         // KK*KK*HEADS
constexpr int HWP = NH * NW;    // 3136
constexpr int NPIX = 8 * HWP;   // 25088
constexpr float SCALE = 0.17677669529663687f;  // 1/sqrt(32)

typedef __hip_bfloat16 bf16;

// ---------------------------------------------------------------------------
// K1: v = x @ Wv. 8 pixels/block, 192 threads (= output channel).
// v stored pixel-major bf16: v[pix*192 + ch].
// ---------------------------------------------------------------------------
__global__ __launch_bounds__(192) void k_vgemm(const float* __restrict__ x,
                                               const float* __restrict__ Wv,
                                               bf16* __restrict__ v) {
  const int p0 = blockIdx.x * 8;
  const int d = threadIdx.x;
  __shared__ float xs[8][NC];
  #pragma unroll
  for (int q = 0; q < 8; ++q) xs[q][d] = x[(size_t)(p0 + q) * NC + d];
  __syncthreads();
  float acc[8];
  #pragma unroll
  for (int q = 0; q < 8; ++q) acc[q] = 0.f;
  for (int k = 0; k < NC; k += 4) {
    float4 xv[8];
    #pragma unroll
    for (int q = 0; q < 8; ++q) xv[q] = *(const float4*)&xs[q][k];
    #pragma unroll
    for (int kk = 0; kk < 4; ++kk) {
      const float wv = Wv[(k + kk) * NC + d];
      #pragma unroll
      for (int q = 0; q < 8; ++q) acc[q] += ((const float*)&xv[q])[kk] * wv;
    }
  }
  #pragma unroll
  for (int q = 0; q < 8; ++q) v[(size_t)(p0 + q) * NC + d] = (bf16)acc[q];
}

// ---------------------------------------------------------------------------
// K2: a = softmax(SCALE*(x@Wa + ba)) over l (rows of 9). 8 pixels/block.
// a stored bf16: a[pix*486 + head*81 + k*9 + l].
// ---------------------------------------------------------------------------
__global__ __launch_bounds__(512) void k_attn(const float* __restrict__ x,
                                              const float* __restrict__ Wa,
                                              const float* __restrict__ ba,
                                              bf16* __restrict__ a) {
  const int p0 = blockIdx.x * 8;
  const int j = threadIdx.x;
  __shared__ float xs[8][NC];
  __shared__ float lg[8][AJ];
  if (j < NC) {
    #pragma unroll
    for (int q = 0; q < 8; ++q) xs[q][j] = x[(size_t)(p0 + q) * NC + j];
  }
  __syncthreads();
  if (j < AJ) {
    const float bav = ba[j];
    float acc[8];
    #pragma unroll
    for (int q = 0; q < 8; ++q) acc[q] = bav;
    for (int k = 0; k < NC; k += 4) {
      float4 xv[8];
      #pragma unroll
      for (int q = 0; q < 8; ++q) xv[q] = *(const float4*)&xs[q][k];
      #pragma unroll
      for (int kk = 0; kk < 4; ++kk) {
        const float wa = Wa[(k + kk) * AJ + j];
        #pragma unroll
        for (int q = 0; q < 8; ++q) acc[q] += ((const float*)&xv[q])[kk] * wa;
      }
    }
    #pragma unroll
    for (int q = 0; q < 8; ++q) lg[q][j] = acc[q] * SCALE;
  }
  __syncthreads();
  if (j < AJ) {
    const int r = (j / 9) * 9;  // softmax row: fixed (head,k), over l
    #pragma unroll
    for (int q = 0; q < 8; ++q) {
      float m = lg[q][r];
      #pragma unroll
      for (int i = 1; i < 9; ++i) m = fmaxf(m, lg[q][r + i]);
      float s = 0.f;
      #pragma unroll
      for (int i = 0; i < 9; ++i) s += __expf(lg[q][r + i] - m);
      a[(size_t)(p0 + q) * AJ + j] = (bf16)(__expf(lg[q][j] - m) / s);
    }
  }
}

// ---------------------------------------------------------------------------
// K3: fused fold-gather + PV + output GEMM. 4 consecutive pixels (same row)
// per block, 192 threads = channels.
// out[b,y,x,ch] = bp[ch] + sum_c Wp[c,ch] * o[c], where
// o[c] = sum_{k: h=y-ki+1,w=x-kj+1 in-bounds} sum_l a[b,(h,w),head(c),k,l]
//         * v[b, h+li-1, w+lj-1, c]  (v=0 OOB)
// ---------------------------------------------------------------------------
__global__ __launch_bounds__(192) void k_out(const bf16* __restrict__ v,
                                             const bf16* __restrict__ a,
                                             const float* __restrict__ Wp,
                                             const float* __restrict__ bp,
                                             float* __restrict__ out) {
  const int p0 = blockIdx.x * 4;
  const int b = p0 / HWP;
  const int yx0 = p0 - b * HWP;
  const int y = yx0 / NW, x0 = yx0 - y * NW;  // 56%4==0 -> same row
  const int ch = threadIdx.x;
  const int head = ch >> 5;

  __shared__ float als[4][NKK][54];  // per pixel, per k: 6 heads x 9 l
  __shared__ float ols[4][NC];

  for (int e = threadIdx.x; e < 4 * AJ; e += 192) {
    const int q = e / AJ, j = e - q * AJ;
    const int hd = j / 81, rem = j - hd * 81, k = rem / 9, l = rem - k * 9;
    const int ki = k / 3, kj = k - ki * 3;
    const int h = y - ki + 1, w = (x0 + q) - kj + 1;
    if ((unsigned)h < NH && (unsigned)w < NW)
      als[q][k][hd * 9 + l] =
          (float)a[(size_t)(b * HWP + h * NW + w) * AJ + j];
  }
  __syncthreads();

  float acc[4] = {0.f, 0.f, 0.f, 0.f};
  for (int k = 0; k < NKK; ++k) {
    const int ki = k / 3, kj = k - ki * 3;
    const int h = y - ki + 1;
    if ((unsigned)h >= NH) continue;  // block-uniform
    #pragma unroll
    for (int l = 0; l < 9; ++l) {
      const int li = l / 3, lj = l - li * 3;
      const int yy = h + li - 1;
      if ((unsigned)yy >= NH) continue;  // block-uniform
      const size_t rowbase = (size_t)(b * HWP + yy * NW) * NC + ch;
      #pragma unroll
      for (int q = 0; q < 4; ++q) {
        const int w = x0 + q - kj + 1;
        const int xx = w + lj - 1;
        if ((unsigned)w >= NW || (unsigned)xx >= NW) continue;
        acc[q] += als[q][k][head * 9 + l] * (float)v[rowbase + (size_t)xx * NC];
      }
    }
  }
  #pragma unroll
  for (int q = 0; q < 4; ++q) ols[q][ch] = acc[q];
  __syncthreads();

  const float bpv = bp[ch];
  float o[4] = {bpv, bpv, bpv, bpv};
  for (int c = 0; c < NC; ++c) {
    const float wp = Wp[c * NC + ch];
    #pragma unroll
    for (int q = 0; q < 4; ++q) o[q] += ols[q][c] * wp;
  }
  #pragma unroll
  for (int q = 0; q < 4; ++q) out[(size_t)(p0 + q) * NC + ch] = o[q];
}

// ---------------------------------------------------------------------------
extern "C" void kernel_launch(void* const* d_in, const int* in_sizes, int n_in,
                              void* d_out, int out_size, void* d_ws,
                              size_t ws_size, hipStream_t stream) {
  (void)in_sizes; (void)n_in; (void)out_size; (void)ws_size;
  const float* x  = (const float*)d_in[0];
  const float* Wv = (const float*)d_in[1];
  const float* Wa = (const float*)d_in[2];
  const float* ba = (const float*)d_in[3];
  const float* Wp = (const float*)d_in[4];
  const float* bp = (const float*)d_in[5];

  bf16* v_ws = (bf16*)d_ws;                                   //  9.63 MB
  bf16* a_ws = (bf16*)((char*)d_ws + (size_t)NPIX * NC * 2);  // 24.39 MB

  k_vgemm<<<NPIX / 8, 192, 0, stream>>>(x, Wv, v_ws);
  k_attn <<<NPIX / 8, 512, 0, stream>>>(x, Wa, ba, a_ws);
  k_out  <<<NPIX / 4, 192, 0, stream>>>(v_ws, a_ws, Wp, bp, (float*)d_out);
}

// Round 3
// 215.820 us; speedup vs baseline: 2.2641x; 2.2641x over previous
//
#include <hip/hip_runtime.h>
#include <hip/hip_bf16.h>

// OutlookAttention: B=8,H=56,W=56,C=192,heads=6,K=3,pad=1 — fp32 in/out
constexpr int NH = 56, NW = 56, NC = 192, AJ = 486;
constexpr int HWP = NH * NW;   // 3136
constexpr int NPIX = 8 * HWP;  // 25088
constexpr float SCALE = 0.17677669529663687f;  // 1/sqrt(32)

typedef unsigned int u32;
typedef __bf16 bf16x8 __attribute__((ext_vector_type(8)));
typedef __bf16 bf16x2 __attribute__((ext_vector_type(2)));
typedef float f32x4 __attribute__((ext_vector_type(4)));

// ---------------------------------------------------------------------------
// P0: transpose + convert weights to bf16, n-major [n][k] for the GEMM B side.
// ---------------------------------------------------------------------------
__global__ __launch_bounds__(256) void k_prep(const float* __restrict__ Wv,
                                              const float* __restrict__ Wa,
                                              const float* __restrict__ Wp,
                                              __bf16* __restrict__ Wvt,
                                              __bf16* __restrict__ Wat,
                                              __bf16* __restrict__ Wpt) {
  const int i = blockIdx.x * 256 + threadIdx.x;
  if (i < 192 * 192) {
    const int n = i / 192, k = i - n * 192;
    Wvt[i] = (__bf16)Wv[k * 192 + n];
    Wpt[i] = (__bf16)Wp[k * 192 + n];
  } else {
    const int j = i - 192 * 192;
    if (j < 486 * 192) {
      const int n = j / 192, k = j - n * 192;
      Wat[j] = (__bf16)Wa[k * 486 + n];
    }
  }
}

// ---------------------------------------------------------------------------
// MFMA GEMM: C[M,Nval] = A[M,192] @ Bt[Nval,192]^T (+bias epilogue).
// BM=128, BN=64, BK=32; 256 thr = 4 waves in 2x2, wave tile 64x32.
// MODE 0: bf16 C.  MODE 1: bf16 C=(acc+bias)*SCALE.  MODE 2: f32 C=acc+bias.
// ---------------------------------------------------------------------------
template <int MODE>
__global__ __launch_bounds__(256) void k_gemm(const void* __restrict__ Ap,
                                              const int a_is_f32,
                                              const __bf16* __restrict__ Bt,
                                              const float* __restrict__ bias,
                                              void* __restrict__ Cp,
                                              const int Nval) {
  __shared__ short As[128 * 32];
  __shared__ short Bs[64 * 32];
  const int m0 = blockIdx.x * 128, n0 = blockIdx.y * 64;
  const int t = threadIdx.x;
  const int lane = t & 63, w = t >> 6, wm = w >> 1, wn = w & 1;
  f32x4 acc[4][2];
  #pragma unroll
  for (int mi = 0; mi < 4; ++mi)
    #pragma unroll
    for (int nj = 0; nj < 2; ++nj) acc[mi][nj] = (f32x4){0.f, 0.f, 0.f, 0.f};

  for (int k0 = 0; k0 < 192; k0 += 32) {
    __syncthreads();
    // A tile: 128 rows x 32 k = 512 chunks of 8 bf16
    #pragma unroll
    for (int i = 0; i < 2; ++i) {
      const int c = t + i * 256;
      const int row = c >> 2, kc = (c & 3) * 8;
      bf16x8 av;
      if (a_is_f32) {
        const float* src = (const float*)Ap + (size_t)(m0 + row) * 192 + k0 + kc;
        const float4 f0 = *(const float4*)src;
        const float4 f1 = *(const float4*)(src + 4);
        av[0] = (__bf16)f0.x; av[1] = (__bf16)f0.y;
        av[2] = (__bf16)f0.z; av[3] = (__bf16)f0.w;
        av[4] = (__bf16)f1.x; av[5] = (__bf16)f1.y;
        av[6] = (__bf16)f1.z; av[7] = (__bf16)f1.w;
      } else {
        av = *(const bf16x8*)((const __bf16*)Ap + (size_t)(m0 + row) * 192 + k0 + kc);
      }
      *(bf16x8*)&As[row * 32 + kc] = av;
    }
    // B tile: 64 rows(n) x 32 k = 256 chunks; zero rows past Nval
    {
      const int row = t >> 2, kc = (t & 3) * 8;
      const int n = n0 + row;
      bf16x8 bv;
      #pragma unroll
      for (int j = 0; j < 8; ++j) bv[j] = (__bf16)0.f;
      if (n < Nval) bv = *(const bf16x8*)&Bt[(size_t)n * 192 + k0 + kc];
      *(bf16x8*)&Bs[row * 32 + kc] = bv;
    }
    __syncthreads();
    bf16x8 af[4], bfr[2];
    #pragma unroll
    for (int mi = 0; mi < 4; ++mi)
      af[mi] = *(const bf16x8*)&As[(wm * 64 + mi * 16 + (lane & 15)) * 32 + (lane >> 4) * 8];
    #pragma unroll
    for (int nj = 0; nj < 2; ++nj)
      bfr[nj] = *(const bf16x8*)&Bs[(wn * 32 + nj * 16 + (lane & 15)) * 32 + (lane >> 4) * 8];
    #pragma unroll
    for (int mi = 0; mi < 4; ++mi)
      #pragma unroll
      for (int nj = 0; nj < 2; ++nj)
        acc[mi][nj] = __builtin_amdgcn_mfma_f32_16x16x32_bf16(af[mi], bfr[nj], acc[mi][nj], 0, 0, 0);
  }
  // epilogue: C/D layout col=lane&15, row=(lane>>4)*4+reg
  const int col_l = lane & 15, rq4 = (lane >> 4) * 4;
  #pragma unroll
  for (int nj = 0; nj < 2; ++nj) {
    const int gn = n0 + wn * 32 + nj * 16 + col_l;
    if (gn >= Nval) continue;
    const float bv = (MODE == 0) ? 0.f : bias[gn];
    #pragma unroll
    for (int mi = 0; mi < 4; ++mi) {
      const int gm = m0 + wm * 64 + mi * 16 + rq4;
      #pragma unroll
      for (int r = 0; r < 4; ++r) {
        const float val = acc[mi][nj][r];
        if (MODE == 0)
          ((__bf16*)Cp)[(size_t)(gm + r) * Nval + gn] = (__bf16)val;
        else if (MODE == 1)
          ((__bf16*)Cp)[(size_t)(gm + r) * Nval + gn] = (__bf16)((val + bv) * SCALE);
        else
          ((float*)Cp)[(size_t)(gm + r) * Nval + gn] = val + bv;
      }
    }
  }
}

// ---------------------------------------------------------------------------
// S: softmax over rows of 9 (in-place, bf16). One thread = 2 rows = 9 dwords.
// ---------------------------------------------------------------------------
__global__ __launch_bounds__(256) void k_smax(__bf16* __restrict__ lg) {
  const int t = blockIdx.x * 256 + threadIdx.x;
  if (t >= NPIX * 27) return;
  u32* p = (u32*)lg + (size_t)t * 9;
  u32 u[9];
  #pragma unroll
  for (int i = 0; i < 9; ++i) u[i] = p[i];
  float v[18];
  #pragma unroll
  for (int i = 0; i < 9; ++i) {
    const bf16x2 b2 = __builtin_bit_cast(bf16x2, u[i]);
    v[2 * i] = (float)b2[0];
    v[2 * i + 1] = (float)b2[1];
  }
  #pragma unroll
  for (int h = 0; h < 2; ++h) {
    float* r = v + h * 9;
    float m = r[0];
    #pragma unroll
    for (int i = 1; i < 9; ++i) m = fmaxf(m, r[i]);
    float s = 0.f;
    #pragma unroll
    for (int i = 0; i < 9; ++i) { r[i] = __expf(r[i] - m); s += r[i]; }
    const float inv = 1.f / s;
    #pragma unroll
    for (int i = 0; i < 9; ++i) r[i] *= inv;
  }
  #pragma unroll
  for (int i = 0; i < 9; ++i) {
    bf16x2 b2;
    b2[0] = (__bf16)v[2 * i];
    b2[1] = (__bf16)v[2 * i + 1];
    p[i] = __builtin_bit_cast(u32, b2);
  }
}

// ---------------------------------------------------------------------------
// K3: delta-collapsed attention gather. 4 pixels (same row) per block.
// o[b,y,x,ch] = sum_{di,dj in [0,5)} wc[q][head][di*5+dj] * v[y+di-2, x+dj-2, ch]
// wc = sum over (ki,kj) with li=ki+di-2, lj=kj+dj-2 valid and source (h,w)
//      in-bounds of softmaxed a. v zero-padded via LDS tile.
// ---------------------------------------------------------------------------
__global__ __launch_bounds__(192) void k_att(const __bf16* __restrict__ v,
                                             const __bf16* __restrict__ a,
                                             __bf16* __restrict__ o) {
  const int p0 = blockIdx.x * 4;
  const int bb = p0 / HWP;
  const int yx0 = p0 - bb * HWP;
  const int y = yx0 / NW, x0 = yx0 - y * NW;  // 56%4==0: same row
  const int t = threadIdx.x;

  __shared__ float vs[40 * 192];    // [cell=dy*8+col][ch], zero-padded
  __shared__ float wc[4][6][28];    // [q][head][di*5+dj] (pad to 28)

  // phase 1: stage 5x8x192 v tile (fp32 in LDS), zero-padded
  for (int u = t; u < 3840; u += 192) {
    const int cell = u / 96, cp = u - cell * 96;
    const int yy = y - 2 + (cell >> 3), xx = x0 - 2 + (cell & 7);
    float2 f2 = make_float2(0.f, 0.f);
    if ((unsigned)yy < (unsigned)NH && (unsigned)xx < (unsigned)NW) {
      const bf16x2 vv = *(const bf16x2*)&v[(size_t)(bb * HWP + yy * NW + xx) * 192 + cp * 2];
      f2.x = (float)vv[0];
      f2.y = (float)vv[1];
    }
    *(float2*)&vs[cell * 192 + cp * 2] = f2;
  }
  // phase 2: collapse a -> 25 coefficients per (q, head)
  if (t < 120) {
    const int q = t / 30, r = t - (t / 30) * 30;
    const int head = r / 5, di = r - (r / 5) * 5;
    float wacc[5] = {0.f, 0.f, 0.f, 0.f, 0.f};
    #pragma unroll
    for (int ki = 0; ki < 3; ++ki) {
      const int li = ki + di - 2;
      const int h = y - ki + 1;
      if ((unsigned)li > 2u || (unsigned)h >= (unsigned)NH) continue;
      #pragma unroll
      for (int kj = 0; kj < 3; ++kj) {
        const int ww = x0 + q - kj + 1;
        if ((unsigned)ww >= (unsigned)NW) continue;
        const size_t abase =
            (size_t)(bb * HWP + h * NW + ww) * AJ + head * 81 + (ki * 3 + kj) * 9 + li * 3;
        #pragma unroll
        for (int dj = 0; dj < 5; ++dj) {
          const int lj = kj + dj - 2;
          if ((unsigned)lj > 2u) continue;  // compile-time
          wacc[dj] += (float)a[abase + lj];
        }
      }
    }
    #pragma unroll
    for (int dj = 0; dj < 5; ++dj) wc[q][head][di * 5 + dj] = wacc[dj];
  }
  __syncthreads();
  // phase 3: 40 v-regs + 25 coefs -> 100 FMA
  const int ch = t, head = ch >> 5;
  float vreg[5][8];
  #pragma unroll
  for (int di = 0; di < 5; ++di)
    #pragma unroll
    for (int col = 0; col < 8; ++col) vreg[di][col] = vs[(di * 8 + col) * 192 + ch];
  #pragma unroll
  for (int q = 0; q < 4; ++q) {
    float coef[25];
    #pragma unroll
    for (int i = 0; i < 6; ++i)
      *(float4*)&coef[i * 4] = *(const float4*)&wc[q][head][i * 4];
    coef[24] = wc[q][head][24];
    float s = 0.f;
    #pragma unroll
    for (int di = 0; di < 5; ++di)
      #pragma unroll
      for (int dj = 0; dj < 5; ++dj) s += coef[di * 5 + dj] * vreg[di][q + dj];
    o[(size_t)(p0 + q) * 192 + ch] = (__bf16)s;
  }
}

// ---------------------------------------------------------------------------
extern "C" void kernel_launch(void* const* d_in, const int* in_sizes, int n_in,
                              void* d_out, int out_size, void* d_ws,
                              size_t ws_size, hipStream_t stream) {
  (void)in_sizes; (void)n_in; (void)out_size; (void)ws_size;
  const float* x  = (const float*)d_in[0];
  const float* Wv = (const float*)d_in[1];
  const float* Wa = (const float*)d_in[2];
  const float* ba = (const float*)d_in[3];
  const float* Wp = (const float*)d_in[4];
  const float* bp = (const float*)d_in[5];

  char* ws = (char*)d_ws;
  __bf16* Wvt = (__bf16*)(ws);                    //  73728 B
  __bf16* Wat = (__bf16*)(ws + 73728);            // 186624 B
  __bf16* Wpt = (__bf16*)(ws + 260352);           //  73728 B
  __bf16* v_ws = (__bf16*)(ws + 334080);          // 9.63 MB
  __bf16* lg_ws = (__bf16*)(ws + 9967872);        // 24.39 MB (logits -> a)
  __bf16* o_ws = (__bf16*)(ws + 34353408);        // 9.63 MB   (total ~42 MB)

  k_prep<<<509, 256, 0, stream>>>(Wv, Wa, Wp, Wvt, Wat, Wpt);
  k_gemm<0><<<dim3(196, 3), 256, 0, stream>>>(x, 1, Wvt, nullptr, v_ws, 192);
  k_gemm<1><<<dim3(196, 8), 256, 0, stream>>>(x, 1, Wat, ba, lg_ws, 486);
  k_smax<<<(NPIX * 27 + 255) / 256, 256, 0, stream>>>(lg_ws);
  k_att<<<NPIX / 4, 192, 0, stream>>>(v_ws, lg_ws, o_ws);
  k_gemm<2><<<dim3(196, 3), 256, 0, stream>>>(o_ws, 0, Wpt, bp, (float*)d_out, 192);
}

// Round 4
// 162.702 us; speedup vs baseline: 3.0033x; 1.3265x over previous
//
#include <hip/hip_runtime.h>
#include <hip/hip_bf16.h>

// OutlookAttention: B=8,H=56,W=56,C=192,heads=6,K=3,pad=1 — fp32 in/out
constexpr int NH = 56, NW = 56, NC = 192, AJ = 486;
constexpr int HWP = NH * NW;   // 3136
constexpr int NPIX = 8 * HWP;  // 25088
constexpr float SCALE = 0.17677669529663687f;  // 1/sqrt(32)

typedef unsigned int u32;
typedef __bf16 bf16x8 __attribute__((ext_vector_type(8)));
typedef __bf16 bf16x2 __attribute__((ext_vector_type(2)));
typedef float f32x4 __attribute__((ext_vector_type(4)));

// ---------------------------------------------------------------------------
// P0: transpose + convert weights to bf16, n-major [n][k].
// ---------------------------------------------------------------------------
__global__ __launch_bounds__(256) void k_prep(const float* __restrict__ Wv,
                                              const float* __restrict__ Wa,
                                              const float* __restrict__ Wp,
                                              __bf16* __restrict__ Wvt,
                                              __bf16* __restrict__ Wat,
                                              __bf16* __restrict__ Wpt) {
  const int i = blockIdx.x * 256 + threadIdx.x;
  if (i < 192 * 192) {
    const int n = i / 192, k = i - n * 192;
    Wvt[i] = (__bf16)Wv[k * 192 + n];
    Wpt[i] = (__bf16)Wp[k * 192 + n];
  } else {
    const int j = i - 192 * 192;
    if (j < 486 * 192) {
      const int n = j / 192, k = j - n * 192;
      Wat[j] = (__bf16)Wa[k * 486 + n];
    }
  }
}

// ---------------------------------------------------------------------------
// MFMA GEMM (pixel-major C): C[M,192] = A[M,192] @ Bt[192,192]^T (+bias).
// BM=128, BN=64, BK=32; 256 thr, 4 waves 2x2. MODE 0: bf16 C. MODE 2: f32 C+b.
// ---------------------------------------------------------------------------
template <int MODE>
__global__ __launch_bounds__(256) void k_gemm(const void* __restrict__ Ap,
                                              const int a_is_f32,
                                              const __bf16* __restrict__ Bt,
                                              const float* __restrict__ bias,
                                              void* __restrict__ Cp,
                                              const int Nval) {
  __shared__ short As[128 * 32];
  __shared__ short Bs[64 * 32];
  const int m0 = blockIdx.x * 128, n0 = blockIdx.y * 64;
  const int t = threadIdx.x;
  const int lane = t & 63, w = t >> 6, wm = w >> 1, wn = w & 1;
  f32x4 acc[4][2];
  #pragma unroll
  for (int mi = 0; mi < 4; ++mi)
    #pragma unroll
    for (int nj = 0; nj < 2; ++nj) acc[mi][nj] = (f32x4){0.f, 0.f, 0.f, 0.f};

  for (int k0 = 0; k0 < 192; k0 += 32) {
    __syncthreads();
    #pragma unroll
    for (int i = 0; i < 2; ++i) {
      const int c = t + i * 256;
      const int row = c >> 2, kc = (c & 3) * 8;
      bf16x8 av;
      if (a_is_f32) {
        const float* src = (const float*)Ap + (size_t)(m0 + row) * 192 + k0 + kc;
        const float4 f0 = *(const float4*)src;
        const float4 f1 = *(const float4*)(src + 4);
        av[0] = (__bf16)f0.x; av[1] = (__bf16)f0.y;
        av[2] = (__bf16)f0.z; av[3] = (__bf16)f0.w;
        av[4] = (__bf16)f1.x; av[5] = (__bf16)f1.y;
        av[6] = (__bf16)f1.z; av[7] = (__bf16)f1.w;
      } else {
        av = *(const bf16x8*)((const __bf16*)Ap + (size_t)(m0 + row) * 192 + k0 + kc);
      }
      *(bf16x8*)&As[row * 32 + kc] = av;
    }
    {
      const int row = t >> 2, kc = (t & 3) * 8;
      const int n = n0 + row;
      bf16x8 bv;
      #pragma unroll
      for (int j = 0; j < 8; ++j) bv[j] = (__bf16)0.f;
      if (n < Nval) bv = *(const bf16x8*)&Bt[(size_t)n * 192 + k0 + kc];
      *(bf16x8*)&Bs[row * 32 + kc] = bv;
    }
    __syncthreads();
    bf16x8 af[4], bfr[2];
    #pragma unroll
    for (int mi = 0; mi < 4; ++mi)
      af[mi] = *(const bf16x8*)&As[(wm * 64 + mi * 16 + (lane & 15)) * 32 + (lane >> 4) * 8];
    #pragma unroll
    for (int nj = 0; nj < 2; ++nj)
      bfr[nj] = *(const bf16x8*)&Bs[(wn * 32 + nj * 16 + (lane & 15)) * 32 + (lane >> 4) * 8];
    #pragma unroll
    for (int mi = 0; mi < 4; ++mi)
      #pragma unroll
      for (int nj = 0; nj < 2; ++nj)
        acc[mi][nj] = __builtin_amdgcn_mfma_f32_16x16x32_bf16(af[mi], bfr[nj], acc[mi][nj], 0, 0, 0);
  }
  const int col_l = lane & 15, rq4 = (lane >> 4) * 4;
  #pragma unroll
  for (int nj = 0; nj < 2; ++nj) {
    const int gn = n0 + wn * 32 + nj * 16 + col_l;
    if (gn >= Nval) continue;
    const float bv = (MODE == 0) ? 0.f : bias[gn];
    #pragma unroll
    for (int mi = 0; mi < 4; ++mi) {
      const int gm = m0 + wm * 64 + mi * 16 + rq4;
      #pragma unroll
      for (int r = 0; r < 4; ++r) {
        const float val = acc[mi][nj][r];
        if (MODE == 0)
          ((__bf16*)Cp)[(size_t)(gm + r) * Nval + gn] = (__bf16)val;
        else
          ((float*)Cp)[(size_t)(gm + r) * Nval + gn] = val + bv;
      }
    }
  }
}

// ---------------------------------------------------------------------------
// G1T: logits TRANSPOSED: lgT[j][pix] = (Wa^T @ x^T + ba)*SCALE, bf16.
// A = Wat[486(pad 512)][192], B = x[NPIX][192] fp32. M=512, N=25088, K=192.
// ---------------------------------------------------------------------------
__global__ __launch_bounds__(256) void k_gemmT(const __bf16* __restrict__ Wat,
                                               const float* __restrict__ x,
                                               const float* __restrict__ ba,
                                               __bf16* __restrict__ lgT) {
  __shared__ short As[128 * 32];
  __shared__ short Bs[64 * 32];
  const int m0 = blockIdx.x * 128, n0 = blockIdx.y * 64;
  const int t = threadIdx.x;
  const int lane = t & 63, w = t >> 6, wm = w >> 1, wn = w & 1;
  f32x4 acc[4][2];
  #pragma unroll
  for (int mi = 0; mi < 4; ++mi)
    #pragma unroll
    for (int nj = 0; nj < 2; ++nj) acc[mi][nj] = (f32x4){0.f, 0.f, 0.f, 0.f};

  for (int k0 = 0; k0 < 192; k0 += 32) {
    __syncthreads();
    // A tile: Wat rows (j), zero-pad past 486
    #pragma unroll
    for (int i = 0; i < 2; ++i) {
      const int c = t + i * 256;
      const int row = c >> 2, kc = (c & 3) * 8;
      bf16x8 av;
      #pragma unroll
      for (int j = 0; j < 8; ++j) av[j] = (__bf16)0.f;
      if (m0 + row < 486)
        av = *(const bf16x8*)&Wat[(size_t)(m0 + row) * 192 + k0 + kc];
      *(bf16x8*)&As[row * 32 + kc] = av;
    }
    // B tile: x pixels, fp32 -> bf16
    {
      const int row = t >> 2, kc = (t & 3) * 8;
      const float* src = x + (size_t)(n0 + row) * 192 + k0 + kc;
      const float4 f0 = *(const float4*)src;
      const float4 f1 = *(const float4*)(src + 4);
      bf16x8 bv;
      bv[0] = (__bf16)f0.x; bv[1] = (__bf16)f0.y;
      bv[2] = (__bf16)f0.z; bv[3] = (__bf16)f0.w;
      bv[4] = (__bf16)f1.x; bv[5] = (__bf16)f1.y;
      bv[6] = (__bf16)f1.z; bv[7] = (__bf16)f1.w;
      *(bf16x8*)&Bs[row * 32 + kc] = bv;
    }
    __syncthreads();
    bf16x8 af[4], bfr[2];
    #pragma unroll
    for (int mi = 0; mi < 4; ++mi)
      af[mi] = *(const bf16x8*)&As[(wm * 64 + mi * 16 + (lane & 15)) * 32 + (lane >> 4) * 8];
    #pragma unroll
    for (int nj = 0; nj < 2; ++nj)
      bfr[nj] = *(const bf16x8*)&Bs[(wn * 32 + nj * 16 + (lane & 15)) * 32 + (lane >> 4) * 8];
    #pragma unroll
    for (int mi = 0; mi < 4; ++mi)
      #pragma unroll
      for (int nj = 0; nj < 2; ++nj)
        acc[mi][nj] = __builtin_amdgcn_mfma_f32_16x16x32_bf16(af[mi], bfr[nj], acc[mi][nj], 0, 0, 0);
  }
  // epilogue: C[m=j][n=pix]; store lgT[j*NPIX + pix] = (acc + ba[j])*SCALE
  const int col_l = lane & 15, rq4 = (lane >> 4) * 4;
  #pragma unroll
  for (int nj = 0; nj < 2; ++nj) {
    const int gn = n0 + wn * 32 + nj * 16 + col_l;  // pixel
    #pragma unroll
    for (int mi = 0; mi < 4; ++mi) {
      const int gmb = m0 + wm * 64 + mi * 16 + rq4;
      #pragma unroll
      for (int r = 0; r < 4; ++r) {
        const int gm = gmb + r;  // j
        if (gm < 486)
          lgT[(size_t)gm * NPIX + gn] = (__bf16)((acc[mi][nj][r] + ba[gm]) * SCALE);
      }
    }
  }
}

// ---------------------------------------------------------------------------
// K-coef: fused softmax + delta-collapse. thread = out pixel, blockIdx.y = head.
// For each window (ki,kj) with valid source pixel: softmax over 9 l's of
// lgT[head*81 + (ki*3+kj)*9 + l][src], scatter into wc[di*5+dj], di=li-ki+2.
// Output wcT[head*25 + c][pix], bf16.
// ---------------------------------------------------------------------------
__global__ __launch_bounds__(256) void k_coef(const __bf16* __restrict__ lgT,
                                              __bf16* __restrict__ wcT) {
  const int p = blockIdx.x * 256 + threadIdx.x;
  const int head = blockIdx.y;
  const int b = p / HWP;
  const int yx = p - b * HWP;
  const int y = yx / NW, x = yx - y * NW;

  float wc[25];
  #pragma unroll
  for (int c = 0; c < 25; ++c) wc[c] = 0.f;

  #pragma unroll
  for (int ki = 0; ki < 3; ++ki) {
    const int h = y - ki + 1;
    if ((unsigned)h >= (unsigned)NH) continue;
    #pragma unroll
    for (int kj = 0; kj < 3; ++kj) {
      const int ww = x - kj + 1;
      if ((unsigned)ww >= (unsigned)NW) continue;
      const int src = b * HWP + h * NW + ww;
      const size_t base = (size_t)((head * 9 + ki * 3 + kj) * 9) * NPIX + src;
      float lt[9];
      #pragma unroll
      for (int l = 0; l < 9; ++l) lt[l] = (float)lgT[base + (size_t)l * NPIX];
      float m = lt[0];
      #pragma unroll
      for (int l = 1; l < 9; ++l) m = fmaxf(m, lt[l]);
      float s = 0.f;
      #pragma unroll
      for (int l = 0; l < 9; ++l) { lt[l] = __expf(lt[l] - m); s += lt[l]; }
      const float inv = 1.f / s;
      #pragma unroll
      for (int l = 0; l < 9; ++l) {
        const int li = l / 3, lj = l - li * 3;
        wc[(li - ki + 2) * 5 + (lj - kj + 2)] += lt[l] * inv;
      }
    }
  }
  #pragma unroll
  for (int c = 0; c < 25; ++c)
    wcT[(size_t)(head * 25 + c) * NPIX + p] = (__bf16)wc[c];
}

// ---------------------------------------------------------------------------
// K-att2: gather. 8 pixels (one row segment) per block, 192 thr = channels.
// o[p0+q][ch] = sum_{di,dj} wc[q][head][di*5+dj] * v[y+di-2][x0+q+dj-2][ch]
// ---------------------------------------------------------------------------
__global__ __launch_bounds__(192) void k_att2(const __bf16* __restrict__ v,
                                              const __bf16* __restrict__ wcT,
                                              __bf16* __restrict__ o) {
  const int p0 = blockIdx.x * 8;
  const int bb = p0 / HWP;
  const int yx0 = p0 - bb * HWP;
  const int y = yx0 / NW, x0 = yx0 - y * NW;  // 56%8==0: same row
  const int t = threadIdx.x;

  __shared__ __bf16 vs[60][192];     // cell = di*12 + col; 23040 B
  __shared__ float wcs[8][6][28];    // [q][head][coef], 5376 B

  // stage v: 60 cells x 24 chunks of bf16x8
  for (int i = t; i < 1440; i += 192) {
    const int cell = i / 24, ck = i - cell * 24;
    const int di = cell / 12, col = cell - di * 12;
    const int yy = y + di - 2, xx = x0 + col - 2;
    bf16x8 val;
    #pragma unroll
    for (int j = 0; j < 8; ++j) val[j] = (__bf16)0.f;
    if ((unsigned)yy < (unsigned)NH && (unsigned)xx < (unsigned)NW)
      val = *(const bf16x8*)&v[(size_t)(bb * HWP + yy * NW + xx) * 192 + ck * 8];
    *(bf16x8*)&vs[cell][ck * 8] = val;
  }
  // stage wc: 150 rows, 8 pixels each (bf16x8 along pix)
  if (t < 150) {
    const int head = t / 25, cc = t - head * 25;
    const bf16x8 w8 = *(const bf16x8*)&wcT[(size_t)t * NPIX + p0];
    #pragma unroll
    for (int q = 0; q < 8; ++q) wcs[q][head][cc] = (float)w8[q];
  }
  __syncthreads();

  const int ch = t, head = ch >> 5;
  float vr[5][12];
  #pragma unroll
  for (int di = 0; di < 5; ++di)
    #pragma unroll
    for (int col = 0; col < 12; ++col) vr[di][col] = (float)vs[di * 12 + col][ch];
  #pragma unroll
  for (int q = 0; q < 8; ++q) {
    float coef[25];
    #pragma unroll
    for (int i = 0; i < 6; ++i)
      *(float4*)&coef[i * 4] = *(const float4*)&wcs[q][head][i * 4];
    coef[24] = wcs[q][head][24];
    float s = 0.f;
    #pragma unroll
    for (int di = 0; di < 5; ++di)
      #pragma unroll
      for (int dj = 0; dj < 5; ++dj) s += coef[di * 5 + dj] * vr[di][q + dj];
    o[(size_t)(p0 + q) * 192 + ch] = (__bf16)s;
  }
}

// ---------------------------------------------------------------------------
extern "C" void kernel_launch(void* const* d_in, const int* in_sizes, int n_in,
                              void* d_out, int out_size, void* d_ws,
                              size_t ws_size, hipStream_t stream) {
  (void)in_sizes; (void)n_in; (void)out_size; (void)ws_size;
  const float* x  = (const float*)d_in[0];
  const float* Wv = (const float*)d_in[1];
  const float* Wa = (const float*)d_in[2];
  const float* ba = (const float*)d_in[3];
  const float* Wp = (const float*)d_in[4];
  const float* bp = (const float*)d_in[5];

  char* ws = (char*)d_ws;
  __bf16* Wvt = (__bf16*)(ws);                 //     73,728 B
  __bf16* Wat = (__bf16*)(ws + 73728);         //    186,624 B
  __bf16* Wpt = (__bf16*)(ws + 260352);        //     73,728 B
  __bf16* v_ws = (__bf16*)(ws + 334080);       //  9,633,792 B
  __bf16* lgT = (__bf16*)(ws + 9967872);       // 24,385,536 B (486 x 25088)
  __bf16* wcT = (__bf16*)(ws + 34353408);      //  7,526,400 B (150 x 25088)
  __bf16* o_ws = (__bf16*)(ws + 9967872);      // aliases lgT (dead after k_coef)
  // total: 41,879,808 B (< 43,987,200 proven available in R3)

  k_prep<<<509, 256, 0, stream>>>(Wv, Wa, Wp, Wvt, Wat, Wpt);
  k_gemm<0><<<dim3(196, 3), 256, 0, stream>>>(x, 1, Wvt, nullptr, v_ws, 192);
  k_gemmT<<<dim3(4, 392), 256, 0, stream>>>(Wat, x, ba, lgT);
  k_coef<<<dim3(98, 6), 256, 0, stream>>>(lgT, wcT);
  k_att2<<<NPIX / 8, 192, 0, stream>>>(v_ws, wcT, o_ws);
  k_gemm<2><<<dim3(196, 3), 256, 0, stream>>>(o_ws, 0, Wpt, bp, (float*)d_out, 192);
}

// Round 5
// 149.685 us; speedup vs baseline: 3.2645x; 1.0870x over previous
//
#include <hip/hip_runtime.h>
#include <hip/hip_bf16.h>

// OutlookAttention: B=8,H=56,W=56,C=192,heads=6,K=3,pad=1 — fp32 in/out
constexpr int NH = 56, NW = 56, NC = 192, AJ = 486;
constexpr int HWP = NH * NW;   // 3136
constexpr int NPIX = 8 * HWP;  // 25088
constexpr float SCALE = 0.17677669529663687f;  // 1/sqrt(32)

typedef __bf16 bf16x8 __attribute__((ext_vector_type(8)));
typedef float f32x4 __attribute__((ext_vector_type(4)));

__device__ __forceinline__ void gload16(const void* g, void* l) {
  __builtin_amdgcn_global_load_lds(
      (const __attribute__((address_space(1))) void*)g,
      (__attribute__((address_space(3))) void*)l, 16, 0, 0);
}

// ---------------------------------------------------------------------------
// P0: weights -> bf16 [n][k] transposed (Wat zero-padded to 512 rows);
//     x -> bf16 (xb), 8 elems/thread.
// ---------------------------------------------------------------------------
__global__ __launch_bounds__(256) void k_prep2(const float* __restrict__ x,
                                               const float* __restrict__ Wv,
                                               const float* __restrict__ Wa,
                                               const float* __restrict__ Wp,
                                               __bf16* __restrict__ xb,
                                               __bf16* __restrict__ Wvt,
                                               __bf16* __restrict__ Wat,
                                               __bf16* __restrict__ Wpt) {
  const int bid = blockIdx.x;
  if (bid < 144) {  // Wvt/Wpt: 192x192
    const int i = bid * 256 + threadIdx.x;
    const int n = i / 192, k = i - n * 192;
    Wvt[i] = (__bf16)Wv[k * 192 + n];
    Wpt[i] = (__bf16)Wp[k * 192 + n];
  } else if (bid < 528) {  // Wat: 512x192 (pad rows 486..511 zero)
    const int i = (bid - 144) * 256 + threadIdx.x;
    const int n = i / 192, k = i - n * 192;
    Wat[i] = (n < 486) ? (__bf16)Wa[k * 486 + n] : (__bf16)0.f;
  } else {  // xb: 4,816,896 elems, 8/thread
    const size_t i = (size_t)(bid - 528) * 256 + threadIdx.x;
    const float* src = x + i * 8;
    const float4 f0 = *(const float4*)src;
    const float4 f1 = *(const float4*)(src + 4);
    bf16x8 o8;
    o8[0] = (__bf16)f0.x; o8[1] = (__bf16)f0.y;
    o8[2] = (__bf16)f0.z; o8[3] = (__bf16)f0.w;
    o8[4] = (__bf16)f1.x; o8[5] = (__bf16)f1.y;
    o8[6] = (__bf16)f1.z; o8[7] = (__bf16)f1.w;
    *(bf16x8*)(xb + i * 8) = o8;
  }
}

// ---------------------------------------------------------------------------
// Square GEMM: C[M,192] = A[M,192] @ Bt[192,192]^T (+bias). All-bf16 operands,
// global_load_lds staging. BM=64, BN=192(full), BK=32; 4 waves 2x2 (32x96).
// MODE 0: bf16 C.  MODE 2: f32 C = acc + bias.
// ---------------------------------------------------------------------------
template <int MODE>
__global__ __launch_bounds__(256) void k_gemm_nn(const __bf16* __restrict__ A,
                                                 const __bf16* __restrict__ Bt,
                                                 const float* __restrict__ bias,
                                                 void* __restrict__ C) {
  __shared__ __bf16 As[64 * 32];
  __shared__ __bf16 Bs[192 * 32];
  const int m0 = blockIdx.x * 64;
  const int t = threadIdx.x, lane = t & 63, w = t >> 6;
  const int wm = w >> 1, wn = w & 1;
  f32x4 acc[2][6];
  #pragma unroll
  for (int mi = 0; mi < 2; ++mi)
    #pragma unroll
    for (int nj = 0; nj < 6; ++nj) acc[mi][nj] = (f32x4){0.f, 0.f, 0.f, 0.f};

  const int cA = w * 64 + lane;
  const int rowA = cA >> 2, kcA = (cA & 3) * 8;

  for (int k0 = 0; k0 < 192; k0 += 32) {
    __syncthreads();
    gload16(A + (size_t)(m0 + rowA) * 192 + k0 + kcA, &As[(w * 64) * 8]);
    #pragma unroll
    for (int i = 0; i < 3; ++i) {
      const int cB = i * 256 + w * 64 + lane;
      const int rowB = cB >> 2, kcB = (cB & 3) * 8;
      gload16(Bt + (size_t)rowB * 192 + k0 + kcB, &Bs[(i * 256 + w * 64) * 8]);
    }
    __syncthreads();
    bf16x8 af[2], bfr[6];
    #pragma unroll
    for (int mi = 0; mi < 2; ++mi)
      af[mi] = *(const bf16x8*)&As[(wm * 32 + mi * 16 + (lane & 15)) * 32 + (lane >> 4) * 8];
    #pragma unroll
    for (int nj = 0; nj < 6; ++nj)
      bfr[nj] = *(const bf16x8*)&Bs[(wn * 96 + nj * 16 + (lane & 15)) * 32 + (lane >> 4) * 8];
    #pragma unroll
    for (int mi = 0; mi < 2; ++mi)
      #pragma unroll
      for (int nj = 0; nj < 6; ++nj)
        acc[mi][nj] = __builtin_amdgcn_mfma_f32_16x16x32_bf16(af[mi], bfr[nj], acc[mi][nj], 0, 0, 0);
  }
  const int col_l = lane & 15, rq4 = (lane >> 4) * 4;
  #pragma unroll
  for (int nj = 0; nj < 6; ++nj) {
    const int gn = wn * 96 + nj * 16 + col_l;
    const float bv = (MODE == 2) ? bias[gn] : 0.f;
    #pragma unroll
    for (int mi = 0; mi < 2; ++mi) {
      const int gm = m0 + wm * 32 + mi * 16 + rq4;
      #pragma unroll
      for (int r = 0; r < 4; ++r) {
        if (MODE == 0)
          ((__bf16*)C)[(size_t)(gm + r) * 192 + gn] = (__bf16)acc[mi][nj][r];
        else
          ((float*)C)[(size_t)(gm + r) * 192 + gn] = acc[mi][nj][r] + bv;
      }
    }
  }
}

// ---------------------------------------------------------------------------
// Logits GEMM (transposed C): lgT[j][pix] = (Wat @ xb^T + ba)*SCALE, bf16.
// A = Wat[512][192], B = xb[NPIX][192]. BM=128, BN=128, BK=32; waves 2x2 (64x64).
// ---------------------------------------------------------------------------
__global__ __launch_bounds__(256) void k_gemmT2(const __bf16* __restrict__ Wat,
                                                const __bf16* __restrict__ xb,
                                                const float* __restrict__ ba,
                                                __bf16* __restrict__ lgT) {
  __shared__ __bf16 As[128 * 32];
  __shared__ __bf16 Bs[128 * 32];
  const int m0 = blockIdx.x * 128, n0 = blockIdx.y * 128;
  const int t = threadIdx.x, lane = t & 63, w = t >> 6;
  const int wm = w >> 1, wn = w & 1;
  f32x4 acc[4][4];
  #pragma unroll
  for (int mi = 0; mi < 4; ++mi)
    #pragma unroll
    for (int nj = 0; nj < 4; ++nj) acc[mi][nj] = (f32x4){0.f, 0.f, 0.f, 0.f};

  for (int k0 = 0; k0 < 192; k0 += 32) {
    __syncthreads();
    #pragma unroll
    for (int i = 0; i < 2; ++i) {
      const int c = i * 256 + w * 64 + lane;
      const int row = c >> 2, kc = (c & 3) * 8;
      gload16(Wat + (size_t)(m0 + row) * 192 + k0 + kc, &As[(i * 256 + w * 64) * 8]);
      gload16(xb + (size_t)(n0 + row) * 192 + k0 + kc, &Bs[(i * 256 + w * 64) * 8]);
    }
    __syncthreads();
    bf16x8 af[4], bfr[4];
    #pragma unroll
    for (int mi = 0; mi < 4; ++mi)
      af[mi] = *(const bf16x8*)&As[(wm * 64 + mi * 16 + (lane & 15)) * 32 + (lane >> 4) * 8];
    #pragma unroll
    for (int nj = 0; nj < 4; ++nj)
      bfr[nj] = *(const bf16x8*)&Bs[(wn * 64 + nj * 16 + (lane & 15)) * 32 + (lane >> 4) * 8];
    #pragma unroll
    for (int mi = 0; mi < 4; ++mi)
      #pragma unroll
      for (int nj = 0; nj < 4; ++nj)
        acc[mi][nj] = __builtin_amdgcn_mfma_f32_16x16x32_bf16(af[mi], bfr[nj], acc[mi][nj], 0, 0, 0);
  }
  const int col_l = lane & 15, rq4 = (lane >> 4) * 4;
  #pragma unroll
  for (int nj = 0; nj < 4; ++nj) {
    const int gn = n0 + wn * 64 + nj * 16 + col_l;  // pixel
    #pragma unroll
    for (int mi = 0; mi < 4; ++mi) {
      const int gmb = m0 + wm * 64 + mi * 16 + rq4;
      #pragma unroll
      for (int r = 0; r < 4; ++r) {
        const int gm = gmb + r;  // j
        if (gm < 486)
          lgT[(size_t)gm * NPIX + gn] = (__bf16)((acc[mi][nj][r] + ba[gm]) * SCALE);
      }
    }
  }
}

// ---------------------------------------------------------------------------
// K-coef: fused softmax + delta-collapse. thread = out pixel, blockIdx.y = head.
// ---------------------------------------------------------------------------
__global__ __launch_bounds__(256) void k_coef(const __bf16* __restrict__ lgT,
                                              __bf16* __restrict__ wcT) {
  const int p = blockIdx.x * 256 + threadIdx.x;
  const int head = blockIdx.y;
  const int b = p / HWP;
  const int yx = p - b * HWP;
  const int y = yx / NW, x = yx - y * NW;

  float wc[25];
  #pragma unroll
  for (int c = 0; c < 25; ++c) wc[c] = 0.f;

  #pragma unroll
  for (int ki = 0; ki < 3; ++ki) {
    const int h = y - ki + 1;
    if ((unsigned)h >= (unsigned)NH) continue;
    #pragma unroll
    for (int kj = 0; kj < 3; ++kj) {
      const int ww = x - kj + 1;
      if ((unsigned)ww >= (unsigned)NW) continue;
      const int src = b * HWP + h * NW + ww;
      const size_t base = (size_t)((head * 9 + ki * 3 + kj) * 9) * NPIX + src;
      float lt[9];
      #pragma unroll
      for (int l = 0; l < 9; ++l) lt[l] = (float)lgT[base + (size_t)l * NPIX];
      float m = lt[0];
      #pragma unroll
      for (int l = 1; l < 9; ++l) m = fmaxf(m, lt[l]);
      float s = 0.f;
      #pragma unroll
      for (int l = 0; l < 9; ++l) { lt[l] = __expf(lt[l] - m); s += lt[l]; }
      const float inv = 1.f / s;
      #pragma unroll
      for (int l = 0; l < 9; ++l) {
        const int li = l / 3, lj = l - li * 3;
        wc[(li - ki + 2) * 5 + (lj - kj + 2)] += lt[l] * inv;
      }
    }
  }
  #pragma unroll
  for (int c = 0; c < 25; ++c)
    wcT[(size_t)(head * 25 + c) * NPIX + p] = (__bf16)wc[c];
}

// ---------------------------------------------------------------------------
// K-att2: gather. 8 pixels/block (same row), 192 thr = channels.
// ---------------------------------------------------------------------------
__global__ __launch_bounds__(192) void k_att2(const __bf16* __restrict__ v,
                                              const __bf16* __restrict__ wcT,
                                              __bf16* __restrict__ o) {
  const int p0 = blockIdx.x * 8;
  const int bb = p0 / HWP;
  const int yx0 = p0 - bb * HWP;
  const int y = yx0 / NW, x0 = yx0 - y * NW;
  const int t = threadIdx.x;

  __shared__ __bf16 vs[60][192];
  __shared__ float wcs[8][6][28];

  for (int i = t; i < 1440; i += 192) {
    const int cell = i / 24, ck = i - cell * 24;
    const int di = cell / 12, col = cell - di * 12;
    const int yy = y + di - 2, xx = x0 + col - 2;
    bf16x8 val;
    #pragma unroll
    for (int j = 0; j < 8; ++j) val[j] = (__bf16)0.f;
    if ((unsigned)yy < (unsigned)NH && (unsigned)xx < (unsigned)NW)
      val = *(const bf16x8*)&v[(size_t)(bb * HWP + yy * NW + xx) * 192 + ck * 8];
    *(bf16x8*)&vs[cell][ck * 8] = val;
  }
  if (t < 150) {
    const int head = t / 25, cc = t - head * 25;
    const bf16x8 w8 = *(const bf16x8*)&wcT[(size_t)t * NPIX + p0];
    #pragma unroll
    for (int q = 0; q < 8; ++q) wcs[q][head][cc] = (float)w8[q];
  }
  __syncthreads();

  const int ch = t, head = ch >> 5;
  float vr[5][12];
  #pragma unroll
  for (int di = 0; di < 5; ++di)
    #pragma unroll
    for (int col = 0; col < 12; ++col) vr[di][col] = (float)vs[di * 12 + col][ch];
  #pragma unroll
  for (int q = 0; q < 8; ++q) {
    float coef[25];
    #pragma unroll
    for (int i = 0; i < 6; ++i)
      *(float4*)&coef[i * 4] = *(const float4*)&wcs[q][head][i * 4];
    coef[24] = wcs[q][head][24];
    float s = 0.f;
    #pragma unroll
    for (int di = 0; di < 5; ++di)
      #pragma unroll
      for (int dj = 0; dj < 5; ++dj) s += coef[di * 5 + dj] * vr[di][q + dj];
    o[(size_t)(p0 + q) * 192 + ch] = (__bf16)s;
  }
}

// ---------------------------------------------------------------------------
extern "C" void kernel_launch(void* const* d_in, const int* in_sizes, int n_in,
                              void* d_out, int out_size, void* d_ws,
                              size_t ws_size, hipStream_t stream) {
  (void)in_sizes; (void)n_in; (void)out_size; (void)ws_size;
  const float* x  = (const float*)d_in[0];
  const float* Wv = (const float*)d_in[1];
  const float* Wa = (const float*)d_in[2];
  const float* ba = (const float*)d_in[3];
  const float* Wp = (const float*)d_in[4];
  const float* bp = (const float*)d_in[5];

  char* ws = (char*)d_ws;  // ws_size = 256 MiB (observed R4); we use 51.5 MB
  __bf16* Wvt = (__bf16*)(ws);                  //     73,728 B
  __bf16* Wat = (__bf16*)(ws + 73728);          //    196,608 B (512x192, padded)
  __bf16* Wpt = (__bf16*)(ws + 270336);         //     73,728 B
  __bf16* xb  = (__bf16*)(ws + 344064);         //  9,633,792 B
  __bf16* v_ws = (__bf16*)(ws + 9977856);       //  9,633,792 B
  __bf16* lgT = (__bf16*)(ws + 19611648);       // 24,385,536 B (486 x 25088)
  __bf16* wcT = (__bf16*)(ws + 43997184);       //  7,526,400 B (150 x 25088)
  __bf16* o_ws = (__bf16*)(ws + 19611648);      // aliases lgT (dead after k_coef)

  k_prep2<<<2880, 256, 0, stream>>>(x, Wv, Wa, Wp, xb, Wvt, Wat, Wpt);
  k_gemm_nn<0><<<392, 256, 0, stream>>>(xb, Wvt, nullptr, v_ws);
  k_gemmT2<<<dim3(4, 196), 256, 0, stream>>>(Wat, xb, ba, lgT);
  k_coef<<<dim3(98, 6), 256, 0, stream>>>(lgT, wcT);
  k_att2<<<NPIX / 8, 192, 0, stream>>>(v_ws, wcT, o_ws);
  k_gemm_nn<2><<<392, 256, 0, stream>>>(o_ws, Wpt, bp, (float*)d_out);
}